// Round 1
// baseline (337.434 us; speedup 1.0000x reference)
//
#include <hip/hip_runtime.h>

#define T 4
#define D 1024
#define NN 256
#define K 64
#define V 32000
// derived
#define VK (V*K)          // 2048000
#define TD (T*D)          // 4096

__device__ __forceinline__ float jexp(float x) {
    // jax_exp: clip(exp(clip(x,-700,700)), 1e-6)
    x = fminf(fmaxf(x, -700.0f), 700.0f);
    return fmaxf(expf(x), 1e-6f);
}

// ---------------- per-(t,k) sum of exp(phi[t,:,k]) over V, fused with CWK copy ----
// grid = T*125 = 500 blocks; each block covers 256 consecutive v-rows of one t.
// Also copies CWK -> CWK_new (float4 grid-stride) so mh_kernel's atomics land on
// an initialized buffer (stream order guarantees completion before mh launches).
__global__ void phi_colsum_copy_kernel(const float* __restrict__ phi,
                                       const float* __restrict__ CWK,
                                       float* __restrict__ S,      // S[T*K], pre-zeroed
                                       float* __restrict__ CWKn)
{
    int blk = blockIdx.x;
    int tid = threadIdx.x;

    // ---- fused copy: 2,048,000 float4 over 500*256 threads = 16 each ----
    {
        const float4* src = (const float4*)CWK;
        float4*       dst = (float4*)CWKn;
        int g = blk * 256 + tid;
        #pragma unroll
        for (int i = 0; i < 16; ++i)
            dst[g + i * 128000] = src[g + i * 128000];
    }

    // ---- column sums of exp(phi) ----
    int t = blk / 125;
    int vbase = (blk % 125) * 256;
    int k = tid & 63;
    int r = tid >> 6;               // 0..3
    const float* base = phi + (size_t)t * VK;
    float s = 0.0f;
    #pragma unroll 4
    for (int it = 0; it < 64; ++it) {
        int v = vbase + it * 4 + r;
        s += expf(base[v * K + k]);         // coalesced: tid-consecutive addrs
    }
    __shared__ float sm[256];
    sm[tid] = s;
    __syncthreads();
    if (tid < 64) {
        float tot = sm[tid] + sm[tid + 64] + sm[tid + 128] + sm[tid + 192];
        atomicAdd(&S[t * K + k], tot);
    }
}

// ---------------- fused eta SGLD + MH resampling + counter scatters ----------------
// one block per (t,d) document, 256 threads = N tokens.
// Wave 0 computes the eta_new row (softmax over K=64) in-block.
__global__ void mh_eta_kernel(const int* __restrict__ W, const int* __restrict__ Z,
                              const int* __restrict__ pwi, const int* __restrict__ ptop,
                              const float* __restrict__ u, const float* __restrict__ phi,
                              const float* __restrict__ eta,
                              const float* __restrict__ alpha,
                              const float* __restrict__ noise_eta,
                              const float* __restrict__ CDK,
                              float* __restrict__ eta_new,
                              float* __restrict__ CDK_new, float* __restrict__ CWK_new,
                              float* __restrict__ CK_new, float* __restrict__ z_out)
{
    int r = blockIdx.x;             // t*D + d
    int t = r >> 10;                // D = 1024
    int n = threadIdx.x;

    __shared__ int   zsh[NN];
    __shared__ float esh[K];
    __shared__ int   hist[K];

    zsh[n] = Z[r * NN + n];

    if (n < 64) {
        // ---- eta SGLD update for this row, wave 0 only ----
        float x = eta[r * K + n];
        float m = x;
        #pragma unroll
        for (int off = 32; off >= 1; off >>= 1)
            m = fmaxf(m, __shfl_xor(m, off, 64));
        float e = expf(x - m);
        float s = e;
        #pragma unroll
        for (int off = 32; off >= 1; off >>= 1)
            s += __shfl_xor(s, off, 64);
        float smx = e / s;
        float grad  = CDK[r * K + n] - (float)NN * smx;
        float prior = alpha[t * K + n] - x;          // ETA_VAR = 1
        float en = x + 0.005f * (grad + prior) + noise_eta[r] * 0.01f;
        esh[n] = en;
        eta_new[r * K + n] = en;
    } else if (n < 128) {
        hist[n - 64] = 0;
    }
    __syncthreads();

    int w     = W[r * NN + n];
    int pre   = zsh[n];
    int prop1 = zsh[pwi[r * NN + n]];

    const float* prow = phi + ((size_t)t * V + w) * K;
    float2 uu = ((const float2*)u)[(size_t)r * NN + n];
    float a1 = jexp(prow[prop1]) / jexp(prow[pre]);
    int k1 = (uu.x < a1) ? prop1 : pre;

    int pt = ptop[r * NN + n];
    float a2 = jexp(esh[pt]) / jexp(esh[k1]);
    int z = (uu.y < a2) ? pt : k1;

    z_out[r * NN + n] = (float)z;

    atomicAdd(&hist[z], 1);
    atomicAdd(&hist[pre], -1);
    if (z != pre) {   // +1 then -1 at same slot is a no-op (counts < 2^24)
        atomicAdd(&CWK_new[((size_t)t * V + w) * K + z],   1.0f);
        atomicAdd(&CWK_new[((size_t)t * V + w) * K + pre], -1.0f);
    }
    __syncthreads();

    if (n < K) {
        int h = hist[n];
        CDK_new[r * K + n] = CDK[r * K + n] + (float)h;   // block owns this row
        if (h != 0) atomicAdd(&CK_new[t * K + n], (float)h);
    }
}

// ---------------- phi SGLD update, all 4 time steps, float4-vectorized ----------------
// grid = VK/(256*4) = 2000 blocks; each thread owns 4 consecutive (v,k) slots
// (never crossing a v-row: K=64 is a multiple of 4).
__global__ void phi_update_kernel(const float* __restrict__ phi,
                                  const float* __restrict__ CWKn,
                                  const float* __restrict__ CKn,
                                  const float* __restrict__ S,
                                  const float* __restrict__ noise_phi,
                                  float* __restrict__ phi_new)
{
    int i4 = blockIdx.x * 256 + threadIdx.x;    // float4 index, < VK/4 = 512000
    int kg = i4 & 15;                           // k-group: covers k = 4*kg .. 4*kg+3
    const float eps = 0.01f;
    const float half_eps = 0.005f;
    const float sig = 1.0f / 1.01f;             // phi_sigma / PHI_VAR

    const float4* phi4  = (const float4*)phi;
    const float4* cwk4  = (const float4*)CWKn;
    const float4* ck4   = (const float4*)CKn;
    const float4* s4    = (const float4*)S;
    float4*       out4  = (float4*)phi_new;

    float4 p0 = phi4[i4];
    float4 p1 = phi4[i4 +     512000];
    float4 p2 = phi4[i4 + 2 * 512000];
    float4 p3 = phi4[i4 + 3 * 512000];

    float4 c0 = cwk4[i4];
    float4 c1 = cwk4[i4 +     512000];
    float4 c2 = cwk4[i4 + 2 * 512000];
    float4 c3 = cwk4[i4 + 3 * 512000];

    float4 ckn0 = ck4[kg],      ckn1 = ck4[16 + kg];
    float4 ckn2 = ck4[32 + kg], ckn3 = ck4[48 + kg];
    float4 ss0 = s4[kg],        ss1 = s4[16 + kg];
    float4 ss2 = s4[32 + kg],   ss3 = s4[48 + kg];

    float np0 = noise_phi[0] * eps, np1 = noise_phi[1] * eps;
    float np2 = noise_phi[2] * eps, np3 = noise_phi[3] * eps;

    float4 o0, o1, o2, o3;
    #pragma unroll
    for (int j = 0; j < 4; ++j) {
        float q0 = (&p0.x)[j], q1 = (&p1.x)[j], q2 = (&p2.x)[j], q3 = (&p3.x)[j];
        float g0 = (&c0.x)[j] - (&ckn0.x)[j] * (expf(q0) / (&ss0.x)[j]);
        float g1 = (&c1.x)[j] - (&ckn1.x)[j] * (expf(q1) / (&ss1.x)[j]);
        float g2 = (&c2.x)[j] - (&ckn2.x)[j] * (expf(q2) / (&ss2.x)[j]);
        float g3 = (&c3.x)[j] - (&ckn3.x)[j] * (expf(q3) / (&ss3.x)[j]);

        float r0 = q0 + half_eps * (g0 + 2.0f * q1 * sig - 2.0f * q0) + np0;
        float r1 = q1 + half_eps * (g1 + q2 + r0 - 2.0f * q1)         + np1;
        float r2 = q2 + half_eps * (g2 + q3 + r1 - 2.0f * q2)         + np2;
        float r3 = q3 + half_eps * (g3 + r2 - q3)                      + np3;

        (&o0.x)[j] = r0; (&o1.x)[j] = r1; (&o2.x)[j] = r2; (&o3.x)[j] = r3;
    }

    out4[i4]              = o0;
    out4[i4 +     512000] = o1;
    out4[i4 + 2 * 512000] = o2;
    out4[i4 + 3 * 512000] = o3;
}

extern "C" void kernel_launch(void* const* d_in, const int* in_sizes, int n_in,
                              void* d_out, int out_size, void* d_ws, size_t ws_size,
                              hipStream_t stream)
{
    const int*   W         = (const int*)  d_in[0];
    const int*   Z         = (const int*)  d_in[1];
    const int*   pwi       = (const int*)  d_in[2];
    const int*   ptop      = (const int*)  d_in[3];
    const float* u_mh      = (const float*)d_in[4];
    const float* noise_eta = (const float*)d_in[5];
    const float* noise_phi = (const float*)d_in[6];
    const float* alpha     = (const float*)d_in[7];
    const float* phi       = (const float*)d_in[8];
    const float* eta       = (const float*)d_in[9];
    const float* CDK       = (const float*)d_in[10];
    const float* CWK       = (const float*)d_in[11];
    const float* CK        = (const float*)d_in[12];

    float* out     = (float*)d_out;
    float* eta_new = out;                               // T*D*K   = 262144
    float* phi_new = out + 262144;                      // T*V*K   = 8192000
    float* CDK_new = out + 8454144;                     // T*D*K   = 262144
    float* CWK_new = out + 8716288;                     // T*V*K   = 8192000
    float* CK_new  = out + 16908288;                    // T*K     = 256
    float* z_out   = out + 16908544;                    // T*D*N   = 1048576

    float* S = (float*)d_ws;                            // T*K softmax denominators

    hipMemsetAsync(S, 0, T * K * sizeof(float), stream);
    hipMemcpyAsync(CK_new, CK, T * K * sizeof(float),
                   hipMemcpyDeviceToDevice, stream);

    phi_colsum_copy_kernel<<<T * 125, 256, 0, stream>>>(phi, CWK, S, CWK_new);
    mh_eta_kernel<<<TD, 256, 0, stream>>>(W, Z, pwi, ptop, u_mh, phi,
                                          eta, alpha, noise_eta, CDK,
                                          eta_new, CDK_new, CWK_new, CK_new, z_out);
    phi_update_kernel<<<VK / 1024, 256, 0, stream>>>(phi, CWK_new, CK_new, S,
                                                     noise_phi, phi_new);
}

// Round 2
// 282.760 us; speedup vs baseline: 1.1934x; 1.1934x over previous
//
#include <hip/hip_runtime.h>

#define T 4
#define D 1024
#define NN 256
#define K 64
#define V 32000
// derived
#define VK (V*K)          // 2048000
#define TD (T*D)          // 4096

__device__ __forceinline__ float jexp(float x) {
    // jax_exp: clip(exp(clip(x,-700,700)), 1e-6)
    x = fminf(fmaxf(x, -700.0f), 700.0f);
    return fmaxf(expf(x), 1e-6f);
}

// ---------------- per-(t,k) sum of exp(phi[t,:,k]) over V, fused with CWK copy ----
// grid = T*125 = 500 blocks; each block covers 256 consecutive v-rows of one t.
__global__ void phi_colsum_copy_kernel(const float* __restrict__ phi,
                                       const float* __restrict__ CWK,
                                       float* __restrict__ S,      // S[T*K], pre-zeroed
                                       float* __restrict__ CWKn)
{
    int blk = blockIdx.x;
    int tid = threadIdx.x;

    // ---- fused copy: 2,048,000 float4 over 500*256 threads = 16 each ----
    {
        const float4* src = (const float4*)CWK;
        float4*       dst = (float4*)CWKn;
        int g = blk * 256 + tid;
        #pragma unroll
        for (int i = 0; i < 16; ++i)
            dst[g + i * 128000] = src[g + i * 128000];
    }

    // ---- column sums of exp(phi) ----
    int t = blk / 125;
    int vbase = (blk % 125) * 256;
    int k = tid & 63;
    int r = tid >> 6;               // 0..3
    const float* base = phi + (size_t)t * VK;
    float s = 0.0f;
    #pragma unroll 4
    for (int it = 0; it < 64; ++it) {
        int v = vbase + it * 4 + r;
        s += expf(base[v * K + k]);         // coalesced: tid-consecutive addrs
    }
    __shared__ float sm[256];
    sm[tid] = s;
    __syncthreads();
    if (tid < 64) {
        float tot = sm[tid] + sm[tid + 64] + sm[tid + 128] + sm[tid + 192];
        atomicAdd(&S[t * K + k], tot);
    }
}

// ---------------- fused eta SGLD + MH resampling + counter scatters ----------------
// one block per (t,d) document, 256 threads = N tokens.
// Phase A: zsh load + eta softmax (wave0). Phase B: MH decisions + LDS hist only.
// Phase C (after last barrier): ALL global writes fire-and-forget, so no barrier
// ever waits on a scattered global atomic ack.
__global__ void mh_eta_kernel(const int* __restrict__ W, const int* __restrict__ Z,
                              const int* __restrict__ pwi, const int* __restrict__ ptop,
                              const float* __restrict__ u, const float* __restrict__ phi,
                              const float* __restrict__ eta,
                              const float* __restrict__ alpha,
                              const float* __restrict__ noise_eta,
                              const float* __restrict__ CDK,
                              float* __restrict__ eta_new,
                              float* __restrict__ CDK_new, float* __restrict__ CWK_new,
                              float* __restrict__ z_out)
{
    int r = blockIdx.x;             // t*D + d
    int t = r >> 10;                // D = 1024
    int n = threadIdx.x;

    __shared__ int   zsh[NN];
    __shared__ float esh[K];
    __shared__ int   hist[K];

    zsh[n] = Z[r * NN + n];

    float cdk = 0.0f;
    if (n < 64) {
        // ---- eta SGLD update for this row, wave 0 only ----
        float x = eta[r * K + n];
        float m = x;
        #pragma unroll
        for (int off = 32; off >= 1; off >>= 1)
            m = fmaxf(m, __shfl_xor(m, off, 64));
        float e = expf(x - m);
        float s = e;
        #pragma unroll
        for (int off = 32; off >= 1; off >>= 1)
            s += __shfl_xor(s, off, 64);
        float smx = e / s;
        cdk = CDK[r * K + n];
        float grad  = cdk - (float)NN * smx;
        float prior = alpha[t * K + n] - x;          // ETA_VAR = 1
        float en = x + 0.005f * (grad + prior) + noise_eta[r] * 0.01f;
        esh[n] = en;
        eta_new[r * K + n] = en;
    } else if (n < 128) {
        hist[n - 64] = 0;
    }
    __syncthreads();

    int w     = W[r * NN + n];
    int pre   = zsh[n];
    int prop1 = zsh[pwi[r * NN + n]];

    const float* prow = phi + ((size_t)t * V + w) * K;
    float2 uu = ((const float2*)u)[(size_t)r * NN + n];
    float a1 = jexp(prow[prop1]) / jexp(prow[pre]);
    int k1 = (uu.x < a1) ? prop1 : pre;

    int pt = ptop[r * NN + n];
    float a2 = jexp(esh[pt]) / jexp(esh[k1]);
    int z = (uu.y < a2) ? pt : k1;

    // only LDS atomics before the final barrier
    atomicAdd(&hist[z], 1);
    atomicAdd(&hist[pre], -1);
    __syncthreads();

    // ---- phase C: global writes, nothing waits on these ----
    z_out[r * NN + n] = (float)z;
    if (z != pre) {   // +1 then -1 at same slot is a no-op
        atomicAdd(&CWK_new[((size_t)t * V + w) * K + z],   1.0f);
        atomicAdd(&CWK_new[((size_t)t * V + w) * K + pre], -1.0f);
    }
    if (n < K) {
        CDK_new[r * K + n] = cdk + (float)hist[n];   // block owns this row
    }
}

// ---------------- CK_new = CK + sum_d hist, via CDK_new - CDK ----------------
// grid = 64 blocks (16 per t), 256 threads. Replaces 262K same-line global
// atomics (16 cache lines!) with a coalesced 2 MB reduction + 4K atomics.
__global__ void ck_reduce_kernel(const float* __restrict__ CDKn,
                                 const float* __restrict__ CDK,
                                 float* __restrict__ CK_new)
{
    int b = blockIdx.x;
    int t = b >> 4;
    int dbase = (b & 15) << 6;          // 16 chunks of 64 d's per t
    int k  = threadIdx.x & 63;
    int dl = threadIdx.x >> 6;          // 0..3
    float s = 0.0f;
    #pragma unroll
    for (int i = 0; i < 16; ++i) {
        int d = dbase + dl + (i << 2);
        size_t idx = ((size_t)(t << 10) + d) * 64 + k;
        s += CDKn[idx] - CDK[idx];      // == hist exactly (up to fp rounding ~1e-3)
    }
    __shared__ float sm[256];
    sm[threadIdx.x] = s;
    __syncthreads();
    if (threadIdx.x < 64) {
        float tot = sm[k] + sm[k + 64] + sm[k + 128] + sm[k + 192];
        atomicAdd(&CK_new[(t << 6) + k], tot);
    }
}

// ---------------- phi SGLD update, all 4 time steps, float4-vectorized ----------------
__global__ void phi_update_kernel(const float* __restrict__ phi,
                                  const float* __restrict__ CWKn,
                                  const float* __restrict__ CKn,
                                  const float* __restrict__ S,
                                  const float* __restrict__ noise_phi,
                                  float* __restrict__ phi_new)
{
    int i4 = blockIdx.x * 256 + threadIdx.x;    // float4 index, < VK/4 = 512000
    int kg = i4 & 15;                           // k-group: covers k = 4*kg .. 4*kg+3
    const float eps = 0.01f;
    const float half_eps = 0.005f;
    const float sig = 1.0f / 1.01f;             // phi_sigma / PHI_VAR

    const float4* phi4  = (const float4*)phi;
    const float4* cwk4  = (const float4*)CWKn;
    const float4* ck4   = (const float4*)CKn;
    const float4* s4    = (const float4*)S;
    float4*       out4  = (float4*)phi_new;

    float4 p0 = phi4[i4];
    float4 p1 = phi4[i4 +     512000];
    float4 p2 = phi4[i4 + 2 * 512000];
    float4 p3 = phi4[i4 + 3 * 512000];

    float4 c0 = cwk4[i4];
    float4 c1 = cwk4[i4 +     512000];
    float4 c2 = cwk4[i4 + 2 * 512000];
    float4 c3 = cwk4[i4 + 3 * 512000];

    float4 ckn0 = ck4[kg],      ckn1 = ck4[16 + kg];
    float4 ckn2 = ck4[32 + kg], ckn3 = ck4[48 + kg];
    float4 ss0 = s4[kg],        ss1 = s4[16 + kg];
    float4 ss2 = s4[32 + kg],   ss3 = s4[48 + kg];

    float np0 = noise_phi[0] * eps, np1 = noise_phi[1] * eps;
    float np2 = noise_phi[2] * eps, np3 = noise_phi[3] * eps;

    float4 o0, o1, o2, o3;
    #pragma unroll
    for (int j = 0; j < 4; ++j) {
        float q0 = (&p0.x)[j], q1 = (&p1.x)[j], q2 = (&p2.x)[j], q3 = (&p3.x)[j];
        float g0 = (&c0.x)[j] - (&ckn0.x)[j] * (expf(q0) / (&ss0.x)[j]);
        float g1 = (&c1.x)[j] - (&ckn1.x)[j] * (expf(q1) / (&ss1.x)[j]);
        float g2 = (&c2.x)[j] - (&ckn2.x)[j] * (expf(q2) / (&ss2.x)[j]);
        float g3 = (&c3.x)[j] - (&ckn3.x)[j] * (expf(q3) / (&ss3.x)[j]);

        float r0 = q0 + half_eps * (g0 + 2.0f * q1 * sig - 2.0f * q0) + np0;
        float r1 = q1 + half_eps * (g1 + q2 + r0 - 2.0f * q1)         + np1;
        float r2 = q2 + half_eps * (g2 + q3 + r1 - 2.0f * q2)         + np2;
        float r3 = q3 + half_eps * (g3 + r2 - q3)                      + np3;

        (&o0.x)[j] = r0; (&o1.x)[j] = r1; (&o2.x)[j] = r2; (&o3.x)[j] = r3;
    }

    out4[i4]              = o0;
    out4[i4 +     512000] = o1;
    out4[i4 + 2 * 512000] = o2;
    out4[i4 + 3 * 512000] = o3;
}

extern "C" void kernel_launch(void* const* d_in, const int* in_sizes, int n_in,
                              void* d_out, int out_size, void* d_ws, size_t ws_size,
                              hipStream_t stream)
{
    const int*   W         = (const int*)  d_in[0];
    const int*   Z         = (const int*)  d_in[1];
    const int*   pwi       = (const int*)  d_in[2];
    const int*   ptop      = (const int*)  d_in[3];
    const float* u_mh      = (const float*)d_in[4];
    const float* noise_eta = (const float*)d_in[5];
    const float* noise_phi = (const float*)d_in[6];
    const float* alpha     = (const float*)d_in[7];
    const float* phi       = (const float*)d_in[8];
    const float* eta       = (const float*)d_in[9];
    const float* CDK       = (const float*)d_in[10];
    const float* CWK       = (const float*)d_in[11];
    const float* CK        = (const float*)d_in[12];

    float* out     = (float*)d_out;
    float* eta_new = out;                               // T*D*K   = 262144
    float* phi_new = out + 262144;                      // T*V*K   = 8192000
    float* CDK_new = out + 8454144;                     // T*D*K   = 262144
    float* CWK_new = out + 8716288;                     // T*V*K   = 8192000
    float* CK_new  = out + 16908288;                    // T*K     = 256
    float* z_out   = out + 16908544;                    // T*D*N   = 1048576

    float* S = (float*)d_ws;                            // T*K softmax denominators

    hipMemsetAsync(S, 0, T * K * sizeof(float), stream);
    hipMemcpyAsync(CK_new, CK, T * K * sizeof(float),
                   hipMemcpyDeviceToDevice, stream);

    phi_colsum_copy_kernel<<<T * 125, 256, 0, stream>>>(phi, CWK, S, CWK_new);
    mh_eta_kernel<<<TD, 256, 0, stream>>>(W, Z, pwi, ptop, u_mh, phi,
                                          eta, alpha, noise_eta, CDK,
                                          eta_new, CDK_new, CWK_new, z_out);
    ck_reduce_kernel<<<64, 256, 0, stream>>>(CDK_new, CDK, CK_new);
    phi_update_kernel<<<VK / 1024, 256, 0, stream>>>(phi, CWK_new, CK_new, S,
                                                     noise_phi, phi_new);
}

// Round 3
// 275.566 us; speedup vs baseline: 1.2245x; 1.0261x over previous
//
#include <hip/hip_runtime.h>

#define T 4
#define D 1024
#define NN 256
#define K 64
#define V 32000
// derived
#define VK (V*K)          // 2048000
#define TD (T*D)          // 4096

__device__ __forceinline__ float jexp(float x) {
    // jax_exp: clip(exp(clip(x,-700,700)), 1e-6)
    x = fminf(fmaxf(x, -700.0f), 700.0f);
    return fmaxf(expf(x), 1e-6f);
}

// ws layout (floats):  S[256] | S_part[500*64] | plus u8[T*V*K] | minus u8[T*V*K]
// byte offsets:        0      | 1024           | 129024         | 129024+8192000
// plus+minus are contiguous: zeroed together as 16,384,000 B (1,024,000 uint4).

// ---------------- colsum partials + delta-buffer zeroing ----------------
// grid = T*125 = 500 blocks; each block covers 256 consecutive v-rows of one t.
__global__ void phi_colsum_kernel(const float* __restrict__ phi,
                                  float* __restrict__ S_part,
                                  unsigned int* __restrict__ delta)  // plus||minus
{
    int blk = blockIdx.x;
    int tid = threadIdx.x;

    // ---- zero the 16 MB plus/minus delta region: 8 uint4 per thread ----
    {
        uint4* dz = (uint4*)delta;
        int g = blk * 256 + tid;
        uint4 z4 = make_uint4(0u, 0u, 0u, 0u);
        #pragma unroll
        for (int i = 0; i < 8; ++i)
            dz[g + i * 128000] = z4;
    }

    // ---- column sums of exp(phi) ----
    int t = blk / 125;
    int vbase = (blk % 125) * 256;
    int k = tid & 63;
    int r = tid >> 6;               // 0..3
    const float* base = phi + (size_t)t * VK;
    float s = 0.0f;
    #pragma unroll 4
    for (int it = 0; it < 64; ++it) {
        int v = vbase + it * 4 + r;
        s += expf(base[v * K + k]);         // coalesced: tid-consecutive addrs
    }
    __shared__ float sm[256];
    sm[tid] = s;
    __syncthreads();
    if (tid < 64) {
        S_part[blk * 64 + tid] = sm[tid] + sm[tid + 64] +
                                 sm[tid + 128] + sm[tid + 192];
    }
}

// ---------------- fused eta SGLD + MH resampling ----------------
// one block per (t,d) document, 256 threads = N tokens.
// CWK counter updates go to packed-u8 plus/minus delta buffers (L2/L3-resident,
// 16 MB) instead of float atomics into the 32 MB CWK_new — kills the random
// 64B HBM read-modify-write traffic that dominated this kernel.
__global__ void mh_eta_kernel(const int* __restrict__ W, const int* __restrict__ Z,
                              const int* __restrict__ pwi, const int* __restrict__ ptop,
                              const float* __restrict__ u, const float* __restrict__ phi,
                              const float* __restrict__ eta,
                              const float* __restrict__ alpha,
                              const float* __restrict__ noise_eta,
                              const float* __restrict__ CDK,
                              float* __restrict__ eta_new,
                              float* __restrict__ CDK_new,
                              unsigned int* __restrict__ plus,
                              unsigned int* __restrict__ minus,
                              float* __restrict__ z_out)
{
    int r = blockIdx.x;             // t*D + d
    int t = r >> 10;                // D = 1024
    int n = threadIdx.x;

    __shared__ int   zsh[NN];
    __shared__ float esh[K];
    __shared__ int   hist[K];

    zsh[n] = Z[r * NN + n];

    float cdk = 0.0f;
    if (n < 64) {
        // ---- eta SGLD update for this row, wave 0 only ----
        float x = eta[r * K + n];
        float m = x;
        #pragma unroll
        for (int off = 32; off >= 1; off >>= 1)
            m = fmaxf(m, __shfl_xor(m, off, 64));
        float e = expf(x - m);
        float s = e;
        #pragma unroll
        for (int off = 32; off >= 1; off >>= 1)
            s += __shfl_xor(s, off, 64);
        float smx = e / s;
        cdk = CDK[r * K + n];
        float grad  = cdk - (float)NN * smx;
        float prior = alpha[t * K + n] - x;          // ETA_VAR = 1
        float en = x + 0.005f * (grad + prior) + noise_eta[r] * 0.01f;
        esh[n] = en;
        eta_new[r * K + n] = en;
    } else if (n < 128) {
        hist[n - 64] = 0;
    }
    __syncthreads();

    int w     = W[r * NN + n];
    int pre   = zsh[n];
    int prop1 = zsh[pwi[r * NN + n]];

    const float* prow = phi + ((size_t)t * V + w) * K;
    float2 uu = ((const float2*)u)[(size_t)r * NN + n];
    float a1 = jexp(prow[prop1]) / jexp(prow[pre]);
    int k1 = (uu.x < a1) ? prop1 : pre;

    int pt = ptop[r * NN + n];
    float a2 = jexp(esh[pt]) / jexp(esh[k1]);
    int z = (uu.y < a2) ? pt : k1;

    // only LDS atomics before the final barrier
    atomicAdd(&hist[z], 1);
    atomicAdd(&hist[pre], -1);
    __syncthreads();

    // ---- phase C: global writes, fire-and-forget ----
    z_out[r * NN + n] = (float)z;
    if (z != pre) {   // net-zero when equal
        size_t rowbase = ((size_t)t * V + w) * 16;   // K/4 u32 per row
        atomicAdd(&plus [rowbase + (z   >> 2)], 1u << ((z   & 3) * 8));
        atomicAdd(&minus[rowbase + (pre >> 2)], 1u << ((pre & 3) * 8));
    }
    if (n < K) {
        CDK_new[r * K + n] = cdk + (float)hist[n];   // block owns this row
    }
}

// ---------------- S finalize + CK_new = CK + sum_d (CDKn - CDK) ----------------
// grid = 4 blocks (one per t), 1024 threads.
__global__ void reduce_kernel(const float* __restrict__ S_part,
                              const float* __restrict__ CDKn,
                              const float* __restrict__ CDK,
                              const float* __restrict__ CK,
                              float* __restrict__ S,
                              float* __restrict__ CK_new)
{
    int t = blockIdx.x;
    int tid = threadIdx.x;

    if (tid < 64) {
        float s = 0.0f;
        #pragma unroll 5
        for (int i = 0; i < 125; ++i)
            s += S_part[(t * 125 + i) * 64 + tid];
        S[t * 64 + tid] = s;
    }

    int k  = tid & 63;
    int dl = tid >> 6;              // 0..15
    float s = 0.0f;
    #pragma unroll 4
    for (int i = 0; i < 64; ++i) {
        int d = dl + i * 16;
        size_t idx = ((size_t)t * D + d) * 64 + k;
        s += CDKn[idx] - CDK[idx];
    }
    __shared__ float sm[1024];
    sm[tid] = s;
    __syncthreads();
    if (tid < 64) {
        float tot = 0.0f;
        #pragma unroll
        for (int j = 0; j < 16; ++j) tot += sm[j * 64 + tid];
        CK_new[t * 64 + tid] = CK[t * 64 + tid] + tot;
    }
}

// ---------------- phi SGLD update + CWK_new materialization ----------------
// grid = VK/1024 = 2000 blocks; each thread owns 4 consecutive (v,k) slots.
__global__ void phi_update_kernel(const float* __restrict__ phi,
                                  const float* __restrict__ CWK,
                                  const unsigned int* __restrict__ plus,
                                  const unsigned int* __restrict__ minus,
                                  const float* __restrict__ CKn,
                                  const float* __restrict__ S,
                                  const float* __restrict__ noise_phi,
                                  float* __restrict__ phi_new,
                                  float* __restrict__ CWK_new)
{
    int i4 = blockIdx.x * 256 + threadIdx.x;    // float4 index, < VK/4 = 512000
    int kg = i4 & 15;                           // k-group: k = 4*kg .. 4*kg+3
    const float eps = 0.01f;
    const float half_eps = 0.005f;
    const float sig = 1.0f / 1.01f;             // phi_sigma / PHI_VAR

    const float4* phi4  = (const float4*)phi;
    const float4* cwk4  = (const float4*)CWK;
    const float4* ck4   = (const float4*)CKn;
    const float4* s4    = (const float4*)S;
    float4*       out4  = (float4*)phi_new;
    float4*       cwkn4 = (float4*)CWK_new;

    float4 p0 = phi4[i4];
    float4 p1 = phi4[i4 +     512000];
    float4 p2 = phi4[i4 + 2 * 512000];
    float4 p3 = phi4[i4 + 3 * 512000];

    float4 c0 = cwk4[i4];
    float4 c1 = cwk4[i4 +     512000];
    float4 c2 = cwk4[i4 + 2 * 512000];
    float4 c3 = cwk4[i4 + 3 * 512000];

    unsigned int pl0 = plus [i4],               mi0 = minus[i4];
    unsigned int pl1 = plus [i4 +     512000],  mi1 = minus[i4 +     512000];
    unsigned int pl2 = plus [i4 + 2 * 512000],  mi2 = minus[i4 + 2 * 512000];
    unsigned int pl3 = plus [i4 + 3 * 512000],  mi3 = minus[i4 + 3 * 512000];

    float4 ckn0 = ck4[kg],      ckn1 = ck4[16 + kg];
    float4 ckn2 = ck4[32 + kg], ckn3 = ck4[48 + kg];
    float4 ss0 = s4[kg],        ss1 = s4[16 + kg];
    float4 ss2 = s4[32 + kg],   ss3 = s4[48 + kg];

    float np0 = noise_phi[0] * eps, np1 = noise_phi[1] * eps;
    float np2 = noise_phi[2] * eps, np3 = noise_phi[3] * eps;

    float4 o0, o1, o2, o3, w0, w1, w2, w3;
    #pragma unroll
    for (int j = 0; j < 4; ++j) {
        int sh = j * 8;
        float q0 = (&p0.x)[j], q1 = (&p1.x)[j], q2 = (&p2.x)[j], q3 = (&p3.x)[j];
        float d0 = (float)((pl0 >> sh) & 255u) - (float)((mi0 >> sh) & 255u);
        float d1 = (float)((pl1 >> sh) & 255u) - (float)((mi1 >> sh) & 255u);
        float d2 = (float)((pl2 >> sh) & 255u) - (float)((mi2 >> sh) & 255u);
        float d3 = (float)((pl3 >> sh) & 255u) - (float)((mi3 >> sh) & 255u);
        float cw0 = (&c0.x)[j] + d0;
        float cw1 = (&c1.x)[j] + d1;
        float cw2 = (&c2.x)[j] + d2;
        float cw3 = (&c3.x)[j] + d3;
        (&w0.x)[j] = cw0; (&w1.x)[j] = cw1; (&w2.x)[j] = cw2; (&w3.x)[j] = cw3;

        float g0 = cw0 - (&ckn0.x)[j] * (expf(q0) / (&ss0.x)[j]);
        float g1 = cw1 - (&ckn1.x)[j] * (expf(q1) / (&ss1.x)[j]);
        float g2 = cw2 - (&ckn2.x)[j] * (expf(q2) / (&ss2.x)[j]);
        float g3 = cw3 - (&ckn3.x)[j] * (expf(q3) / (&ss3.x)[j]);

        float r0 = q0 + half_eps * (g0 + 2.0f * q1 * sig - 2.0f * q0) + np0;
        float r1 = q1 + half_eps * (g1 + q2 + r0 - 2.0f * q1)         + np1;
        float r2 = q2 + half_eps * (g2 + q3 + r1 - 2.0f * q2)         + np2;
        float r3 = q3 + half_eps * (g3 + r2 - q3)                      + np3;

        (&o0.x)[j] = r0; (&o1.x)[j] = r1; (&o2.x)[j] = r2; (&o3.x)[j] = r3;
    }

    out4[i4]              = o0;
    out4[i4 +     512000] = o1;
    out4[i4 + 2 * 512000] = o2;
    out4[i4 + 3 * 512000] = o3;

    cwkn4[i4]              = w0;
    cwkn4[i4 +     512000] = w1;
    cwkn4[i4 + 2 * 512000] = w2;
    cwkn4[i4 + 3 * 512000] = w3;
}

extern "C" void kernel_launch(void* const* d_in, const int* in_sizes, int n_in,
                              void* d_out, int out_size, void* d_ws, size_t ws_size,
                              hipStream_t stream)
{
    const int*   W         = (const int*)  d_in[0];
    const int*   Z         = (const int*)  d_in[1];
    const int*   pwi       = (const int*)  d_in[2];
    const int*   ptop      = (const int*)  d_in[3];
    const float* u_mh      = (const float*)d_in[4];
    const float* noise_eta = (const float*)d_in[5];
    const float* noise_phi = (const float*)d_in[6];
    const float* alpha     = (const float*)d_in[7];
    const float* phi       = (const float*)d_in[8];
    const float* eta       = (const float*)d_in[9];
    const float* CDK       = (const float*)d_in[10];
    const float* CWK       = (const float*)d_in[11];
    const float* CK        = (const float*)d_in[12];

    float* out     = (float*)d_out;
    float* eta_new = out;                               // T*D*K   = 262144
    float* phi_new = out + 262144;                      // T*V*K   = 8192000
    float* CDK_new = out + 8454144;                     // T*D*K   = 262144
    float* CWK_new = out + 8716288;                     // T*V*K   = 8192000
    float* CK_new  = out + 16908288;                    // T*K     = 256
    float* z_out   = out + 16908544;                    // T*D*N   = 1048576

    float* ws      = (float*)d_ws;
    float* S       = ws;                                // 256 floats
    float* S_part  = ws + 256;                          // 500*64 floats
    unsigned int* plus  = (unsigned int*)(ws + 256 + 32000);   // 8,192,000 B
    unsigned int* minus = plus + 2048000;                      // 8,192,000 B

    phi_colsum_kernel<<<T * 125, 256, 0, stream>>>(phi, S_part, plus);
    mh_eta_kernel<<<TD, 256, 0, stream>>>(W, Z, pwi, ptop, u_mh, phi,
                                          eta, alpha, noise_eta, CDK,
                                          eta_new, CDK_new, plus, minus, z_out);
    reduce_kernel<<<4, 1024, 0, stream>>>(S_part, CDK_new, CDK, CK, S, CK_new);
    phi_update_kernel<<<VK / 1024, 256, 0, stream>>>(phi, CWK, plus, minus,
                                                     CK_new, S, noise_phi,
                                                     phi_new, CWK_new);
}